// Round 15
// baseline (98.866 us; speedup 1.0000x reference)
//
#include <hip/hip_runtime.h>

// N=100000 nodes, D=64, P=Q=32, E=3200000 edges.
// 5-dispatch pipeline:
//  1. prep_count   : bin_count (512 blks) + intensity->bf16/fp8 (64) + Wbig (1)
//  2. scanA        : per-bucket scan of 512 per-block counts -> lofs, T[b]
//  3. bin_scatter  : computes G from T in-LDS; LDS counting-sort scatter
//  4. bucket_fused : computes G[b] from T; node-sort in LDS + 2-way-split
//                    fp8 gather (uint2 loads, 2 edges/group in flight) -> xnbr
//  5. node_mfma    : bf16 MFMA + zero-LDS D-fragment epilogue

#define RLOG 7
#define RNODES 128
#define NBLK 512
#define CAP 6144
#define CHUNK 6272   // >= ceil4(E/NBLK) = 6252
#define CVB 64       // cvt blocks inside prep_count

typedef __attribute__((ext_vector_type(8))) short short8;
typedef __attribute__((ext_vector_type(4))) float f32x4;
typedef __attribute__((ext_vector_type(2))) float f32x2;

__device__ __forceinline__ unsigned short f2bf(float x) {
    union { float f; unsigned u; } v; v.f = x;
    unsigned r = v.u + 0x7FFF + ((v.u >> 16) & 1);  // RNE
    return (unsigned short)(r >> 16);
}

// ---- fp8 pack/unpack: prefer HW cvt (self-consistent encode/decode) ----
#if __has_builtin(__builtin_amdgcn_cvt_pk_fp8_f32) && __has_builtin(__builtin_amdgcn_cvt_pk_f32_fp8)
__device__ __forceinline__ unsigned pack4_fp8(float a, float b, float c, float d) {
    int p = __builtin_amdgcn_cvt_pk_fp8_f32(a, b, 0, false);
    p = __builtin_amdgcn_cvt_pk_fp8_f32(c, d, p, true);
    return (unsigned)p;
}
__device__ __forceinline__ void unpack4_fp8(unsigned w, float& a, float& b, float& c, float& d) {
    f32x2 lo = __builtin_amdgcn_cvt_pk_f32_fp8(w, false);
    f32x2 hi = __builtin_amdgcn_cvt_pk_f32_fp8(w, true);
    a = lo[0]; b = lo[1]; c = hi[0]; d = hi[1];
}
#else
__device__ __forceinline__ unsigned char f2fp8_sw(float x) {
    union { float f; unsigned u; } v; v.f = x;
    unsigned s = (v.u >> 24) & 0x80;
    float ax = fminf(fabsf(x), 448.0f);
    union { float f; unsigned u; } w; w.f = ax;
    int e = (int)((w.u >> 23) & 0xFF) - 127;
    if (e < -6) {
        int mi = (int)(ax * 512.0f + 0.5f);
        if (mi > 7) mi = 7;
        return (unsigned char)(s | mi);
    }
    unsigned mant = (w.u >> 20) & 7;
    unsigned rest = w.u & 0xFFFFF;
    unsigned rnd = (rest > 0x80000u) || (rest == 0x80000u && (mant & 1));
    unsigned enc = ((unsigned)(e + 7) << 3) | mant;
    enc += rnd;
    if (enc > 0x7Eu) enc = 0x7Eu;
    return (unsigned char)(s | enc);
}
__device__ __forceinline__ float fp82f_sw(unsigned char b) {
    unsigned e = (b >> 3) & 0xF, m = b & 7;
    float mag;
    if (e == 0) mag = (float)m * 0.001953125f;
    else {
        union { unsigned u; float f; } v;
        v.u = ((e + 120u) << 23) | (m << 20);
        mag = v.f;
    }
    return (b & 0x80) ? -mag : mag;
}
__device__ __forceinline__ unsigned pack4_fp8(float a, float b, float c, float d) {
    return (unsigned)f2fp8_sw(a) | ((unsigned)f2fp8_sw(b) << 8) |
           ((unsigned)f2fp8_sw(c) << 16) | ((unsigned)f2fp8_sw(d) << 24);
}
__device__ __forceinline__ void unpack4_fp8(unsigned w, float& a, float& b, float& c, float& d) {
    a = fp82f_sw((unsigned char)(w & 0xFF));
    b = fp82f_sw((unsigned char)((w >> 8) & 0xFF));
    c = fp82f_sw((unsigned char)((w >> 16) & 0xFF));
    d = fp82f_sw((unsigned char)((w >> 24) & 0xFF));
}
#endif

__device__ __forceinline__ float softplus_fast(float x) {
    float t = __expf(-fabsf(x));
    return fmaxf(x, 0.0f) + __logf(1.0f + t);
}

__device__ __forceinline__ float tanh_fast(float x) {
    float t = __expf(-2.0f * fabsf(x));
    float m = (1.0f - t) * __builtin_amdgcn_rcpf(1.0f + t);
    return __builtin_copysignf(m, x);
}

__device__ __forceinline__ int chunk_of(int E) {
    return (((E + NBLK - 1) / NBLK) + 3) & ~3;
}

// ---- 1. fused prep: bin_count | intensity cvt | weight stack
__global__ __launch_bounds__(1024) void prep_count(
    const int* __restrict__ edst, int* __restrict__ cnt,
    const float* __restrict__ x, unsigned short* __restrict__ ybf,
    unsigned* __restrict__ yfp8, int total4,
    const float* __restrict__ Wf, const float* __restrict__ Wg,
    const float* __restrict__ Wz, const float* __restrict__ WA,
    unsigned short* __restrict__ wbig,
    int E, int B) {
    int tid = threadIdx.x, blk = blockIdx.x;
    if (blk < NBLK) {
        __shared__ int lcnt[1024];
        for (int b = tid; b < B; b += 1024) lcnt[b] = 0;
        __syncthreads();
        int chunk = chunk_of(E);
        int start = blk * chunk;
        int end = min(E, start + chunk);
        int v4s = start >> 2, v4e = end >> 2;
        for (int i = v4s + tid; i < v4e; i += 1024) {
            int4 d = ((const int4*)edst)[i];
            atomicAdd(&lcnt[d.x >> RLOG], 1);
            atomicAdd(&lcnt[d.y >> RLOG], 1);
            atomicAdd(&lcnt[d.z >> RLOG], 1);
            atomicAdd(&lcnt[d.w >> RLOG], 1);
        }
        for (int i = (v4e << 2) + tid; i < end; i += 1024)
            atomicAdd(&lcnt[edst[i] >> RLOG], 1);
        __syncthreads();
        for (int b = tid; b < B; b += 1024) cnt[b * NBLK + blk] = lcnt[b];
    } else if (blk < NBLK + CVB) {
        int cb = blk - NBLK;
        for (int i = cb * 1024 + tid; i < total4; i += CVB * 1024) {
            float4 v = ((const float4*)x)[i];
            ushort4 r;
            r.x = f2bf(v.x); r.y = f2bf(v.y); r.z = f2bf(v.z); r.w = f2bf(v.w);
            ((ushort4*)ybf)[i] = r;
            yfp8[i] = pack4_fp8(v.x, v.y, v.z, v.w);
        }
    } else {
        for (int idx = tid; idx < 192 * 64; idx += 1024) {
            int r = idx >> 6, k = idx & 63;
            float v = (r < 64)  ? Wf[r * 64 + k]
                    : (r < 128) ? Wg[(r - 64) * 64 + k]
                    : (r < 160) ? Wz[(r - 128) * 64 + k]
                                : WA[(r - 160) * 64 + k];
            wbig[idx] = f2bf(v);
        }
    }
}

// ---- 2. scanA: per-bucket exclusive scan over NBLK per-block counts
__global__ __launch_bounds__(512) void scanA(const int* __restrict__ cnt,
                                             int* __restrict__ lofs,
                                             int* __restrict__ T) {
    int t = threadIdx.x, b = blockIdx.x;
    int lane = t & 63, wave = t >> 6;   // 8 waves
    int v = cnt[b * NBLK + t];
    int incl = v;
    #pragma unroll
    for (int off = 1; off < 64; off <<= 1) {
        int w = __shfl_up(incl, off);
        if (lane >= off) incl += w;
    }
    __shared__ int wt[8];
    if (lane == 63) wt[wave] = incl;
    __syncthreads();
    int woff = 0;
    for (int i = 0; i < wave; ++i) woff += wt[i];
    int excl = woff + incl - v;
    lofs[b * NBLK + t] = excl;
    if (t == NBLK - 1) T[b] = excl + v;
}

// ---- 3. scatter: in-LDS G from T + LDS counting sort, coalesced writes
__global__ __launch_bounds__(1024) void bin_scatter(const int* __restrict__ esrc,
                                                    const int* __restrict__ edst,
                                                    const int* __restrict__ cnt,
                                                    const int* __restrict__ lofs,
                                                    const int* __restrict__ T,
                                                    int* __restrict__ binned,
                                                    int E, int B) {
    __shared__ unsigned sl_pack[CHUNK];
    __shared__ unsigned short sl_bkt[CHUNK];
    __shared__ int lsc[1024];
    __shared__ int base[1024];
    __shared__ int wtot[16];
    int tid = threadIdx.x, blk = blockIdx.x;
    int lane = tid & 63, wave = tid >> 6;

    // scan 1: G = exclusive prefix of T (bucket totals)
    int tv = (tid < B) ? T[tid] : 0;
    int tincl = tv;
    #pragma unroll
    for (int off = 1; off < 64; off <<= 1) {
        int w = __shfl_up(tincl, off);
        if (lane >= off) tincl += w;
    }
    if (lane == 63) wtot[wave] = tincl;
    __syncthreads();
    int twoff = 0;
    for (int i = 0; i < wave; ++i) twoff += wtot[i];
    int Gv = twoff + tincl - tv;
    __syncthreads();

    // scan 2: this block's per-bucket local exclusive start
    int v = (tid < B) ? cnt[tid * NBLK + blk] : 0;
    int incl = v;
    #pragma unroll
    for (int off = 1; off < 64; off <<= 1) {
        int w = __shfl_up(incl, off);
        if (lane >= off) incl += w;
    }
    if (lane == 63) wtot[wave] = incl;
    __syncthreads();
    int woff = 0;
    for (int i = 0; i < wave; ++i) woff += wtot[i];
    int excl = woff + incl - v;
    if (tid < B) {
        base[tid] = Gv + lofs[tid * NBLK + blk] - excl;
        lsc[tid] = excl;
    }
    __syncthreads();

    int chunk = chunk_of(E);
    int start = blk * chunk;
    int end = min(E, start + chunk);
    int m = end - start;
    int v4s = start >> 2, v4e = end >> 2;
    for (int i = v4s + tid; i < v4e; i += 1024) {
        int4 d = ((const int4*)edst)[i];
        int4 s = ((const int4*)esrc)[i];
        int b0 = d.x >> RLOG, b1 = d.y >> RLOG, b2 = d.z >> RLOG, b3 = d.w >> RLOG;
        int p0 = atomicAdd(&lsc[b0], 1);
        int p1 = atomicAdd(&lsc[b1], 1);
        int p2 = atomicAdd(&lsc[b2], 1);
        int p3 = atomicAdd(&lsc[b3], 1);
        sl_pack[p0] = ((unsigned)(d.x & (RNODES - 1)) << 17) | (unsigned)s.x;
        sl_pack[p1] = ((unsigned)(d.y & (RNODES - 1)) << 17) | (unsigned)s.y;
        sl_pack[p2] = ((unsigned)(d.z & (RNODES - 1)) << 17) | (unsigned)s.z;
        sl_pack[p3] = ((unsigned)(d.w & (RNODES - 1)) << 17) | (unsigned)s.w;
        sl_bkt[p0] = (unsigned short)b0;
        sl_bkt[p1] = (unsigned short)b1;
        sl_bkt[p2] = (unsigned short)b2;
        sl_bkt[p3] = (unsigned short)b3;
    }
    for (int i = (v4e << 2) + tid; i < end; i += 1024) {
        int d = edst[i];
        int s = esrc[i];
        int b = d >> RLOG;
        int p = atomicAdd(&lsc[b], 1);
        sl_pack[p] = ((unsigned)(d & (RNODES - 1)) << 17) | (unsigned)s;
        sl_bkt[p] = (unsigned short)b;
    }
    __syncthreads();

    for (int i = tid; i < m; i += 1024) {
        binned[base[sl_bkt[i]] + i] = (int)sl_pack[i];
    }
}

// ---- 4. fused: node sort (LDS) + split-gather (2 edges/8-lane group)
__global__ __launch_bounds__(1024) void bucket_fused(
    const int* __restrict__ binned, const int* __restrict__ T,
    const unsigned* __restrict__ ifp8,
    unsigned short* __restrict__ xnbr, int E, int N, int B) {
    __shared__ int sl[CAP];
    __shared__ int sl2[CAP];
    __shared__ int c128[RNODES];
    __shared__ int pos[RNODES];
    __shared__ int dstart[RNODES];
    __shared__ int ddeg[RNODES];
    __shared__ int wtot[16];
    __shared__ int s_start;
    int tid = threadIdx.x;
    int b = blockIdx.x;
    int lane = tid & 63, wave = tid >> 6;

    // compute start = G[b] via block scan of T
    int tv = (tid < B) ? T[tid] : 0;
    int tincl = tv;
    #pragma unroll
    for (int off = 1; off < 64; off <<= 1) {
        int w = __shfl_up(tincl, off);
        if (lane >= off) tincl += w;
    }
    if (lane == 63) wtot[wave] = tincl;
    __syncthreads();
    int twoff = 0;
    for (int i = 0; i < wave; ++i) twoff += wtot[i];
    if (tid == b) s_start = twoff + tincl - tv;
    __syncthreads();
    int start = s_start;
    int m = min((tid == tid ? 0 : 0) + ((b < B) ? ((int)T[b]) : 0), CAP);
    // (T[b] is this bucket's size; clamp to CAP)

    for (int i = tid; i < m; i += 1024) sl[i] = binned[start + i];
    if (tid < RNODES) c128[tid] = 0;
    __syncthreads();
    for (int i = tid; i < m; i += 1024) atomicAdd(&c128[sl[i] >> 17], 1);
    __syncthreads();

    int x = 0, incl = 0;
    if (tid < RNODES) { x = c128[tid]; incl = x; }
    #pragma unroll
    for (int off = 1; off < RNODES; off <<= 1) {
        int y = 0;
        if (tid < RNODES && tid >= off) y = c128[tid - off];
        __syncthreads();
        if (tid < RNODES) { incl += y; c128[tid] = incl; }
        __syncthreads();
    }
    if (tid < RNODES) {
        int excl = incl - x;
        pos[tid] = excl;
        dstart[tid] = excl;
        ddeg[tid] = x;
    }
    __syncthreads();
    for (int i = tid; i < m; i += 1024) {
        int e = sl[i];
        int p = atomicAdd(&pos[e >> 17], 1);
        sl2[p] = e & 131071;
    }
    __syncthreads();

    // gather: 128 groups of 8 lanes; lane-halves process alternating edges,
    // each lane owns 8 features via uint2 (8B) loads -> 2x MLP
    int g = tid >> 3;
    int l = tid & 7;
    int half = l >> 2;         // 0: even edge slots, 1: odd
    int fl = l & 3;            // uint2 index in row (features fl*8..fl*8+7)
    int node = b * RNODES + g;
    int st = dstart[g];
    int dg = ddeg[g];
    float a0 = 0.f, a1 = 0.f, a2 = 0.f, a3 = 0.f;
    float a4 = 0.f, a5 = 0.f, a6 = 0.f, a7 = 0.f;
    int j = 0;
    for (; j + 7 < dg; j += 8) {
        int s0 = sl2[st + j + half];
        int s1 = sl2[st + j + 2 + half];
        int s2 = sl2[st + j + 4 + half];
        int s3 = sl2[st + j + 6 + half];
        uint2 w0 = ((const uint2*)ifp8)[s0 * 4 + fl];
        uint2 w1 = ((const uint2*)ifp8)[s1 * 4 + fl];
        uint2 w2 = ((const uint2*)ifp8)[s2 * 4 + fl];
        uint2 w3 = ((const uint2*)ifp8)[s3 * 4 + fl];
        float x0, x1, x2, x3;
        unpack4_fp8(w0.x, x0, x1, x2, x3); a0 += x0; a1 += x1; a2 += x2; a3 += x3;
        unpack4_fp8(w0.y, x0, x1, x2, x3); a4 += x0; a5 += x1; a6 += x2; a7 += x3;
        unpack4_fp8(w1.x, x0, x1, x2, x3); a0 += x0; a1 += x1; a2 += x2; a3 += x3;
        unpack4_fp8(w1.y, x0, x1, x2, x3); a4 += x0; a5 += x1; a6 += x2; a7 += x3;
        unpack4_fp8(w2.x, x0, x1, x2, x3); a0 += x0; a1 += x1; a2 += x2; a3 += x3;
        unpack4_fp8(w2.y, x0, x1, x2, x3); a4 += x0; a5 += x1; a6 += x2; a7 += x3;
        unpack4_fp8(w3.x, x0, x1, x2, x3); a0 += x0; a1 += x1; a2 += x2; a3 += x3;
        unpack4_fp8(w3.y, x0, x1, x2, x3); a4 += x0; a5 += x1; a6 += x2; a7 += x3;
    }
    for (j = j + half; j < dg; j += 2) {
        int s0 = sl2[st + j];
        uint2 w0 = ((const uint2*)ifp8)[s0 * 4 + fl];
        float x0, x1, x2, x3;
        unpack4_fp8(w0.x, x0, x1, x2, x3); a0 += x0; a1 += x1; a2 += x2; a3 += x3;
        unpack4_fp8(w0.y, x0, x1, x2, x3); a4 += x0; a5 += x1; a6 += x2; a7 += x3;
    }
    // combine lane halves (lanes l and l^4 are in the same 8-lane group)
    a0 += __shfl_xor(a0, 4); a1 += __shfl_xor(a1, 4);
    a2 += __shfl_xor(a2, 4); a3 += __shfl_xor(a3, 4);
    a4 += __shfl_xor(a4, 4); a5 += __shfl_xor(a5, 4);
    a6 += __shfl_xor(a6, 4); a7 += __shfl_xor(a7, 4);
    if (half == 0 && node < N) {
        float inv = (dg > 0) ? 1.0f / (float)dg : 0.0f;
        short8 r;
        r[0] = (short)f2bf(a0 * inv); r[1] = (short)f2bf(a1 * inv);
        r[2] = (short)f2bf(a2 * inv); r[3] = (short)f2bf(a3 * inv);
        r[4] = (short)f2bf(a4 * inv); r[5] = (short)f2bf(a5 * inv);
        r[6] = (short)f2bf(a6 * inv); r[7] = (short)f2bf(a7 * inv);
        ((short8*)xnbr)[(size_t)node * 4 + fl] = r;
    }
}

// ---- 5. MFMA node kernel, zero-LDS epilogue in D-fragment layout.
__global__ __launch_bounds__(256, 4) void node_mfma(
    const float* __restrict__ u,
    const unsigned short* __restrict__ ibf,
    const unsigned short* __restrict__ xnbr,
    const unsigned short* __restrict__ wbig,
    const float* __restrict__ bfp, const float* __restrict__ bgp,
    const float* __restrict__ bzp, const float* __restrict__ bAp,
    float* __restrict__ out, int N) {
    int tid = threadIdx.x;
    int lane = tid & 63;
    int wave = tid >> 6;
    int tile = blockIdx.x * 4 + wave;
    int ntiles = N >> 4;
    if (tile >= ntiles) return;

    int col = lane & 15;
    int kg = lane >> 4;
    int n0 = tile * 16;
    int node = n0 + col;

    const float* ub = u + (size_t)node * 64 + kg * 8;
    float4 u0 = *(const float4*)(ub);
    float4 u1 = *(const float4*)(ub + 4);
    float4 u2 = *(const float4*)(ub + 32);
    float4 u3 = *(const float4*)(ub + 36);
    short8 au0, au1;
    au0[0]=(short)f2bf(u0.x); au0[1]=(short)f2bf(u0.y); au0[2]=(short)f2bf(u0.z); au0[3]=(short)f2bf(u0.w);
    au0[4]=(short)f2bf(u1.x); au0[5]=(short)f2bf(u1.y); au0[6]=(short)f2bf(u1.z); au0[7]=(short)f2bf(u1.w);
    au1[0]=(short)f2bf(u2.x); au1[1]=(short)f2bf(u2.y); au1[2]=(short)f2bf(u2.z); au1[3]=(short)f2bf(u2.w);
    au1[4]=(short)f2bf(u3.x); au1[5]=(short)f2bf(u3.y); au1[6]=(short)f2bf(u3.z); au1[7]=(short)f2bf(u3.w);
    short8 ax0 = *(const short8*)(ibf  + (size_t)node * 32 + kg * 8);
    short8 ax1 = *(const short8*)(xnbr + (size_t)node * 32 + kg * 8);

    const short8* wb = (const short8*)wbig;
    f32x4 acc[12];
    #pragma unroll
    for (int t = 0; t < 12; ++t) acc[t] = (f32x4){0.f, 0.f, 0.f, 0.f};
    #pragma unroll
    for (int t = 0; t < 12; ++t) {
        short8 a0 = (t < 10) ? au0 : ax0;
        short8 a1 = (t < 10) ? au1 : ax1;
        short8 b0 = wb[(t * 16 + col) * 8 + kg];
        short8 b1 = wb[(t * 16 + col) * 8 + 4 + kg];
        acc[t] = __builtin_amdgcn_mfma_f32_16x16x32_bf16(a0, b0, acc[t], 0, 0, 0);
        acc[t] = __builtin_amdgcn_mfma_f32_16x16x32_bf16(a1, b1, acc[t], 0, 0, 0);
    }

    float bfv[4], bgv[4], bzv[4];
    #pragma unroll
    for (int s = 0; s < 4; ++s) {
        int j = s * 16 + col;
        bfv[s] = bfp[j];
        bgv[s] = bgp[j];
        bzv[s] = (s < 2) ? bzp[j] : bAp[j - 32];
    }

    float du01[2][4], uv01[2][4];
    float ar[4], br[4];
    #pragma unroll
    for (int r = 0; r < 4; ++r) { ar[r] = 0.f; br[r] = 0.f; }
    #pragma unroll
    for (int s = 0; s < 2; ++s) {
        #pragma unroll
        for (int r = 0; r < 4; ++r) {
            int nd = n0 + kg * 4 + r;
            float uu = u[(size_t)nd * 64 + s * 16 + col];
            float fpre = acc[s][r] + bfv[s];
            float gpre = acc[4 + s][r] + bgv[s];
            float zpre = acc[8 + s][r] + bzv[s];
            float Fu = softplus_fast(fpre);
            float Gu = softplus_fast(gpre);
            float zv = tanh_fast(zpre);
            float d = -Fu * uu + Gu * zv;
            du01[s][r] = d;
            uv01[s][r] = uu;
            ar[r] = fmaf(d, uu, ar[r]);
            br[r] = fmaf(uu, uu, br[r]);
        }
    }
    #pragma unroll
    for (int off = 1; off < 16; off <<= 1) {
        #pragma unroll
        for (int r = 0; r < 4; ++r) {
            ar[r] += __shfl_xor(ar[r], off);
            br[r] += __shfl_xor(br[r], off);
        }
    }
    float coef[4];
    #pragma unroll
    for (int r = 0; r < 4; ++r) coef[r] = ar[r] * __builtin_amdgcn_rcpf(br[r]);

    #pragma unroll
    for (int s = 0; s < 2; ++s) {
        #pragma unroll
        for (int r = 0; r < 4; ++r) {
            int nd = n0 + kg * 4 + r;
            out[(size_t)nd * 64 + s * 16 + col] = du01[s][r] - coef[r] * uv01[s][r];
        }
    }
    #pragma unroll
    for (int s = 2; s < 4; ++s) {
        #pragma unroll
        for (int r = 0; r < 4; ++r) {
            int nd = n0 + kg * 4 + r;
            float uu = u[(size_t)nd * 64 + s * 16 + col];
            float fpre = acc[s][r] + bfv[s];
            float gpre = acc[4 + s][r] + bgv[s];
            float zpre = acc[8 + s][r] + bzv[s];
            float Fu = softplus_fast(fpre);
            float Gu = softplus_fast(gpre);
            float zv = fmaxf(zpre, 0.0f);
            out[(size_t)nd * 64 + s * 16 + col] = -Fu * uu + Gu * zv;
        }
    }
}

extern "C" void kernel_launch(void* const* d_in, const int* in_sizes, int n_in,
                              void* d_out, int out_size, void* d_ws, size_t ws_size,
                              hipStream_t stream) {
    const float* u         = (const float*)d_in[0];
    const float* intensity = (const float*)d_in[1];
    const int*   esrc      = (const int*)d_in[2];
    const int*   edst      = (const int*)d_in[3];
    const float* Wf        = (const float*)d_in[4];
    const float* bf        = (const float*)d_in[5];
    const float* Wg        = (const float*)d_in[6];
    const float* bg        = (const float*)d_in[7];
    const float* Wz        = (const float*)d_in[8];
    const float* bz        = (const float*)d_in[9];
    const float* WA        = (const float*)d_in[10];
    const float* bA        = (const float*)d_in[11];

    int N = in_sizes[0] / 64;
    int E = in_sizes[2];
    int B = (N + RNODES - 1) / RNODES;          // 782
    int M = B * NBLK;                            // 400384

    int* cnt    = (int*)d_ws;                    // M
    int* lofs   = cnt + M;                       // M
    int* T      = lofs + M;                      // 1024
    int* binned = T + 1024;                      // E
    unsigned short* xnbr = (unsigned short*)(binned + E);   // N*32
    unsigned short* wbig = xnbr + (size_t)N * 32;           // 192*64
    unsigned short* ibf  = wbig + 192 * 64;                 // N*32
    unsigned* ifp8 = (unsigned*)(ibf + (size_t)N * 32);     // N*8 uints

    prep_count<<<NBLK + CVB + 1, 1024, 0, stream>>>(
        edst, cnt, intensity, ibf, ifp8, N * 8, Wf, Wg, Wz, WA, wbig, E, B);
    scanA<<<B, 512, 0, stream>>>(cnt, lofs, T);
    bin_scatter<<<NBLK, 1024, 0, stream>>>(esrc, edst, cnt, lofs, T, binned, E, B);
    bucket_fused<<<B, 1024, 0, stream>>>(binned, T, ifp8, xnbr, E, N, B);
    int ntiles = N / 16;
    int nblocks = (ntiles + 3) / 4;
    node_mfma<<<nblocks, 256, 0, stream>>>(u, ibf, xnbr, wbig,
                                           bf, bg, bz, bA, (float*)d_out, N);
}